// Round 2
// baseline (9117.921 us; speedup 1.0000x reference)
//
#include <hip/hip_runtime.h>
#include <hip/hip_bf16.h>

#define NN 8192
#define DD 256
#define LAYERS 2
#define KPOLY 10

#define BM 64
#define BN 64
#define BK 32

// epilogue modes
#define MODE_Z1  0   // C = -invdeg[r] * acc
#define MODE_ZK  1   // C = -2*invdeg[r] * acc - Cin
#define MODE_ADD 2   // C += acc
#define MODE_SET 3   // C  = acc

__global__ __launch_bounds__(256) void gemm_fused(
    const float* __restrict__ A, int lda,
    const float* __restrict__ B, int ldb,
    int Kdim,
    float* C,                 // no __restrict__: may alias Cin
    const float* Cin,         // only used in MODE_ZK
    const float* __restrict__ invdeg,
    int mode)
{
    __shared__ float Ast[BK][BM + 4];   // transposed A tile, stride 68 floats (16B-aligned rows)
    __shared__ float Bs[BK][BN];

    const int tid = threadIdx.x;
    const int bm = blockIdx.x * BM;
    const int bn = blockIdx.y * BN;

    const int tx = tid & 15;        // output col group
    const int ty = tid >> 4;        // output row group
    const int ar = tid >> 3;        // A stage row (0..31)
    const int ac = tid & 7;         // A stage col4 (0..7)
    const int br = tid >> 4;        // B stage row (0..15)
    const int bc = tid & 15;        // B stage col4

    const float* Abase  = A + (size_t)(bm + ar) * lda + ac * 4;
    const float* Abase2 = Abase + (size_t)32 * lda;
    const float* Bbase  = B + (size_t)br * ldb + bn + bc * 4;
    const float* Bbase2 = Bbase + (size_t)16 * ldb;

    float acc[4][4] = {};

    float4 pa0 = *(const float4*)(Abase);
    float4 pa1 = *(const float4*)(Abase2);
    float4 pb0 = *(const float4*)(Bbase);
    float4 pb1 = *(const float4*)(Bbase2);

    const int nch = Kdim / BK;
    for (int ch = 0; ch < nch; ++ch) {
        // stage prefetched regs -> LDS (A transposed)
        Ast[ac * 4 + 0][ar]      = pa0.x;
        Ast[ac * 4 + 1][ar]      = pa0.y;
        Ast[ac * 4 + 2][ar]      = pa0.z;
        Ast[ac * 4 + 3][ar]      = pa0.w;
        Ast[ac * 4 + 0][ar + 32] = pa1.x;
        Ast[ac * 4 + 1][ar + 32] = pa1.y;
        Ast[ac * 4 + 2][ar + 32] = pa1.z;
        Ast[ac * 4 + 3][ar + 32] = pa1.w;
        *(float4*)&Bs[br][bc * 4]      = pb0;
        *(float4*)&Bs[br + 16][bc * 4] = pb1;
        __syncthreads();

        // prefetch next chunk while computing this one
        if (ch + 1 < nch) {
            const size_t koff = (size_t)(ch + 1) * BK;
            pa0 = *(const float4*)(Abase + koff);
            pa1 = *(const float4*)(Abase2 + koff);
            pb0 = *(const float4*)(Bbase + koff * ldb);
            pb1 = *(const float4*)(Bbase2 + koff * ldb);
        }

#pragma unroll
        for (int kk = 0; kk < BK; ++kk) {
            float4 av4 = *(const float4*)&Ast[kk][ty * 4];
            float4 bv4 = *(const float4*)&Bs[kk][tx * 4];
            float av[4] = {av4.x, av4.y, av4.z, av4.w};
            float bv[4] = {bv4.x, bv4.y, bv4.z, bv4.w};
#pragma unroll
            for (int i = 0; i < 4; ++i)
#pragma unroll
                for (int j = 0; j < 4; ++j)
                    acc[i][j] = fmaf(av[i], bv[j], acc[i][j]);
        }
        __syncthreads();
    }

    const int row0 = bm + ty * 4;
    const int col  = bn + tx * 4;

    if (mode == MODE_Z1) {
#pragma unroll
        for (int i = 0; i < 4; ++i) {
            const int r = row0 + i;
            const float s = -invdeg[r];
            float4 v;
            v.x = s * acc[i][0]; v.y = s * acc[i][1];
            v.z = s * acc[i][2]; v.w = s * acc[i][3];
            *(float4*)&C[(size_t)r * DD + col] = v;
        }
    } else if (mode == MODE_ZK) {
#pragma unroll
        for (int i = 0; i < 4; ++i) {
            const int r = row0 + i;
            const float s = -2.0f * invdeg[r];
            float4 cin = *(const float4*)&Cin[(size_t)r * DD + col];
            float4 v;
            v.x = s * acc[i][0] - cin.x; v.y = s * acc[i][1] - cin.y;
            v.z = s * acc[i][2] - cin.z; v.w = s * acc[i][3] - cin.w;
            *(float4*)&C[(size_t)r * DD + col] = v;
        }
    } else if (mode == MODE_ADD) {
#pragma unroll
        for (int i = 0; i < 4; ++i) {
            const int r = row0 + i;
            float4 cv = *(const float4*)&C[(size_t)r * DD + col];
            cv.x += acc[i][0]; cv.y += acc[i][1];
            cv.z += acc[i][2]; cv.w += acc[i][3];
            *(float4*)&C[(size_t)r * DD + col] = cv;
        }
    } else {
#pragma unroll
        for (int i = 0; i < 4; ++i) {
            const int r = row0 + i;
            float4 v;
            v.x = acc[i][0]; v.y = acc[i][1];
            v.z = acc[i][2]; v.w = acc[i][3];
            *(float4*)&C[(size_t)r * DD + col] = v;
        }
    }
}

__global__ __launch_bounds__(256) void invdeg_kernel(const float* __restrict__ deg,
                                                     float* __restrict__ invdeg)
{
    int i = blockIdx.x * blockDim.x + threadIdx.x;
    if (i < NN) invdeg[i] = 1.0f / deg[i];
}

// out = tanh(U + bias)  (float32 destination — d_out is f32, proven round 1)
__global__ __launch_bounds__(256) void act_kernel(const float* __restrict__ U,
                                                  const float* __restrict__ bias,
                                                  float* __restrict__ out)
{
    int idx = (blockIdx.x * blockDim.x + threadIdx.x) * 4;
    float4 u = *(const float4*)&U[idx];
    float4 bb = *(const float4*)&bias[idx];
    float4 t;
    t.x = tanhf(u.x + bb.x);
    t.y = tanhf(u.y + bb.y);
    t.z = tanhf(u.z + bb.z);
    t.w = tanhf(u.w + bb.w);
    *(float4*)&out[idx] = t;
}

extern "C" void kernel_launch(void* const* d_in, const int* in_sizes, int n_in,
                              void* d_out, int out_size, void* d_ws, size_t ws_size,
                              hipStream_t stream)
{
    const float* X   = (const float*)d_in[0];   // [N, D]
    const float* adj = (const float*)d_in[1];   // [N, N]
    const float* deg = (const float*)d_in[2];   // [N]
    const float* W   = (const float*)d_in[3];   // [L, K, D, D]
    const float* b   = (const float*)d_in[4];   // [L, N, D]
    float* out = (float*)d_out;                 // f32 output

    float* ws = (float*)d_ws;
    const size_t MAT = (size_t)NN * DD;         // 2M floats = 8 MB
    float* Zbuf[3] = { ws, ws + MAT, ws + 2 * MAT };
    float* U    = ws + 3 * MAT;
    float* Xb   = ws + 4 * MAT;
    float* invd = ws + 5 * MAT;

    const dim3 ggrid(NN / BM, DD / BN);   // (128, 4)
    const dim3 gblk(256);

    invdeg_kernel<<<NN / 256, 256, 0, stream>>>(deg, invd);

    for (int l = 0; l < LAYERS; ++l) {
        const float* Xin = (l == 0) ? X : Xb;
        const float* Wl = W + (size_t)l * KPOLY * DD * DD;

        // U = Xin @ W[l][0]
        gemm_fused<<<ggrid, gblk, 0, stream>>>(Xin, DD, Wl, DD, DD,
                                               U, nullptr, nullptr, MODE_SET);
        // Z1 = -(1/deg) * (adj @ Xin)
        gemm_fused<<<ggrid, gblk, 0, stream>>>(adj, NN, Xin, DD, NN,
                                               Zbuf[0], nullptr, invd, MODE_Z1);
        // U += Z1 @ W[l][1]
        gemm_fused<<<ggrid, gblk, 0, stream>>>(Zbuf[0], DD, Wl + (size_t)1 * DD * DD, DD, DD,
                                               U, nullptr, nullptr, MODE_ADD);

        int im2 = -1;          // buffer index of Z_{k-2} (-1 == Xin)
        int im1 = 0;           // buffer index of Z_{k-1}
        int ifree = 1;
        for (int k = 2; k < KPOLY; ++k) {
            const float* zm1 = Zbuf[im1];
            const float* zm2 = (im2 < 0) ? Xin : Zbuf[im2];
            float* znew = Zbuf[ifree];
            // Znew = -2/deg * (adj @ zm1) - zm2
            gemm_fused<<<ggrid, gblk, 0, stream>>>(adj, NN, zm1, DD, NN,
                                                   znew, zm2, invd, MODE_ZK);
            // U += Znew @ W[l][k]
            gemm_fused<<<ggrid, gblk, 0, stream>>>(znew, DD, Wl + (size_t)k * DD * DD, DD, DD,
                                                   U, nullptr, nullptr, MODE_ADD);
            const int newfree = (im2 < 0) ? 2 : im2;
            im2 = im1; im1 = ifree; ifree = newfree;
        }

        // X_next = tanh(U + b[l]) ; final layer writes d_out (f32)
        float* dst = (l == LAYERS - 1) ? out : Xb;
        act_kernel<<<(NN * DD) / (256 * 4), 256, 0, stream>>>(
            U, b + (size_t)l * NN * DD, dst);
    }
}